// Round 6
// baseline (740.220 us; speedup 1.0000x reference)
//
#include <hip/hip_runtime.h>

#define DD 128            // feature dim
#define LRELU_SLOPE 0.2f
#define SE 1024           // degrees per scan block
#define NBK 256           // dst-range buckets for CSR build
#define BCAP 8192         // bucket capacity (mean ~3.3K, +13 sigma)

typedef unsigned short u16;
typedef unsigned int   u32;
typedef __attribute__((ext_vector_type(8))) short short8;   // 8 bf16 (4 VGPRs)
typedef __attribute__((ext_vector_type(4))) float f32x4;    // MFMA C/D

__device__ __forceinline__ u16 f2bf(float f) {              // RNE f32->bf16
    union { float f; u32 u; } v; v.f = f;
    u32 r = (v.u + 0x7fffu + ((v.u >> 16) & 1u)) >> 16;
    return (u16)r;
}
__device__ __forceinline__ float bf2f(u32 hi16) {           // bf16 bits -> f32
    union { u32 u; float f; } v; v.u = hi16 << 16;
    return v.f;
}

// ---------------------------------------------------------------------------
// Edge-index dtype detection (int64 vs int32) — high words all zero => int64.
// ---------------------------------------------------------------------------
__global__ void detect_i64_kernel(const int* __restrict__ ei32, int* __restrict__ flag, int E) {
    __shared__ int any_nz;
    if (threadIdx.x == 0) any_nz = 0;
    __syncthreads();
    int nz = 0;
    int kmax = (E < 4096) ? E : 4096;
    for (int k = threadIdx.x; k < kmax; k += blockDim.x)
        if (ei32[2 * k + 1] != 0) nz = 1;
    if (nz) atomicOr(&any_nz, 1);
    __syncthreads();
    if (threadIdx.x == 0) *flag = any_nz ? 0 : 1;
}

__device__ __forceinline__ int load_dst(const void* ei, int is64, int E, int i) {
    return is64 ? (int)((const long long*)ei)[E + i] : ((const int*)ei)[E + i];
}
__device__ __forceinline__ int load_src(const void* ei, int is64, int E, int i) {
    return is64 ? (int)((const long long*)ei)[i] : ((const int*)ei)[i];
}

__global__ void zero2_kernel(int* __restrict__ a, int na, int* __restrict__ b, int nb) {
    int i = blockIdx.x * blockDim.x + threadIdx.x;
    if (i < na) a[i] = 0;
    if (i < nb) b[i] = 0;
}

// ---------------------------------------------------------------------------
// CSR build, locality-bucketed:
//  K1: per edge -> deg histogram + append (dst,src) to dst-range bucket
//  scan (3 stages, hierarchical)
//  K3: per bucket -> cursor scatter, esrc writes confined to ~13KB window
// ---------------------------------------------------------------------------
__global__ void bucket_hist_kernel(const void* __restrict__ ei, const int* __restrict__ flag,
                                   int* __restrict__ deg, int* __restrict__ bcnt,
                                   int2* __restrict__ pairs, int E, int N, int bdiv) {
    int i = blockIdx.x * blockDim.x + threadIdx.x;
    int tot = E + N;
    if (i >= tot) return;
    int s, d;
    if (i < E) { int f = *flag; s = load_src(ei, f, E, i); d = load_dst(ei, f, E, i); }
    else       { s = d = i - E; }
    if ((unsigned)d >= (unsigned)N || (unsigned)s >= (unsigned)N) return;  // defensive
    atomicAdd(&deg[d], 1);
    int b = d / bdiv;
    int pos = atomicAdd(&bcnt[b], 1);
    if (pos < BCAP) pairs[(size_t)b * BCAP + pos] = make_int2(d, s);
    else            atomicSub(&deg[d], 1);     // keep CSR self-consistent (never expected)
}

__global__ __launch_bounds__(256) void bucket_scatter_kernel(const int2* __restrict__ pairs,
                                                             const int* __restrict__ bcnt,
                                                             int* __restrict__ cursor,
                                                             int* __restrict__ esrc) {
    int b = blockIdx.x;
    int n = bcnt[b]; if (n > BCAP) n = BCAP;
    const int2* p = pairs + (size_t)b * BCAP;
    for (int i = threadIdx.x; i < n; i += 256) {
        int2 e = p[i];
        int pos = atomicAdd(&cursor[e.x], 1);
        esrc[pos] = e.y;
    }
}

// stage 1: per-block sums of 1024 degrees (coalesced)
__global__ __launch_bounds__(256) void block_sum_kernel(const int* __restrict__ deg,
                                                        int* __restrict__ bsum, int N) {
    int t = threadIdx.x;
    int base = blockIdx.x * SE;
    int s = 0;
#pragma unroll
    for (int i = 0; i < 4; ++i) {
        int idx = base + i * 256 + t;
        if (idx < N) s += deg[idx];
    }
#pragma unroll
    for (int m = 1; m < 64; m <<= 1) s += __shfl_xor(s, m, 64);
    __shared__ int ws[4];
    if ((t & 63) == 0) ws[t >> 6] = s;
    __syncthreads();
    if (t == 0) bsum[blockIdx.x] = ws[0] + ws[1] + ws[2] + ws[3];
}

// stage 2: single small block — exclusive scan of nb (<=256) block sums
__global__ __launch_bounds__(256) void scan_bsum_kernel(const int* __restrict__ bsum,
                                                        int* __restrict__ boff, int nb) {
    int t = threadIdx.x;
    int lane = t & 63;
    int v = (t < nb) ? bsum[t] : 0;
    int incl = v;
#pragma unroll
    for (int m = 1; m < 64; m <<= 1) {
        int u = __shfl_up(incl, m, 64);
        if (lane >= m) incl += u;
    }
    __shared__ int wtot[4];
    if (lane == 63) wtot[t >> 6] = incl;
    __syncthreads();
    int woff = 0;
    for (int w = 0; w < (t >> 6); ++w) woff += wtot[w];
    if (t < nb) boff[t] = incl - v + woff;
}

// stage 3: intra-block exclusive scan (4 elems/thread via int4) + block offset
__global__ __launch_bounds__(256) void scan_write_kernel(const int* __restrict__ deg,
                                                         const int* __restrict__ boff,
                                                         int* __restrict__ rowp,
                                                         int* __restrict__ cursor, int N) {
    int t = threadIdx.x;
    int base = blockIdx.x * SE + t * 4;
    int v0 = 0, v1 = 0, v2 = 0, v3 = 0;
    if (base + 3 < N) {
        int4 q = *(const int4*)(deg + base);
        v0 = q.x; v1 = q.y; v2 = q.z; v3 = q.w;
    } else {
        if (base + 0 < N) v0 = deg[base + 0];
        if (base + 1 < N) v1 = deg[base + 1];
        if (base + 2 < N) v2 = deg[base + 2];
    }
    int tsum = v0 + v1 + v2 + v3;
    int lane = t & 63;
    int incl = tsum;
#pragma unroll
    for (int m = 1; m < 64; m <<= 1) {
        int u = __shfl_up(incl, m, 64);
        if (lane >= m) incl += u;
    }
    __shared__ int wtot[4];
    if (lane == 63) wtot[t >> 6] = incl;
    __syncthreads();
    int woff = 0;
    for (int w = 0; w < (t >> 6); ++w) woff += wtot[w];
    int run = boff[blockIdx.x] + woff + incl - tsum;
    int vs[4] = {v0, v1, v2, v3};
    int idx = base;
#pragma unroll
    for (int i = 0; i < 4; ++i, ++idx) {
        if (idx < N) {
            rowp[idx] = run; cursor[idx] = run; run += vs[i];
            if (idx == N - 1) rowp[N] = run;
        }
    }
}

// ---------------------------------------------------------------------------
// Weight pre-pack: W panels (f32 row-major [K][128]) -> bf16 MFMA B-fragment
// order. Fragment (panel, t, c): lane l, elem j holds
//   W[t*32 + (l>>4)*8 + j][c*16 + (l&15)]
// flat: Wpack[(((panel*4 + t)*8 + c)*64 + l)*8 + j]
// panels: 0=We, 1=Wp[0:128], 2=Wp[128:256], 3=Wd. 128 blocks x 64 threads.
// ---------------------------------------------------------------------------
__global__ void pack_w_kernel(const float* __restrict__ We, const float* __restrict__ Wp,
                              const float* __restrict__ Wd, u16* __restrict__ Wpack) {
    int blk = blockIdx.x;
    int l = threadIdx.x;
    int panel = blk >> 5, t = (blk >> 3) & 3, c = blk & 7;
    const float* src = (panel == 0) ? We : (panel == 3) ? Wd : Wp + (size_t)(panel - 1) * 128 * DD;
    u16* dst = Wpack + ((((size_t)panel * 4 + t) * 8 + c) * 64 + l) * 8;
    int krow = t * 32 + (l >> 4) * 8;
    int col = c * 16 + (l & 15);
#pragma unroll
    for (int j = 0; j < 8; ++j)
        dst[j] = f2bf(src[(size_t)(krow + j) * DD + col]);
}

// ---------------------------------------------------------------------------
// MFMA GEMM + attention scores.
// H[row] = Xcat[row] @ W  (bf16 MFMA, f32 acc); Ss/Sd = H . a_s / a_d (f32).
// Block = 256 thr = 4 waves; each wave one 16-row x 128-col tile.
// ---------------------------------------------------------------------------
__device__ __forceinline__ short8 load_afrag(const float* p) {
    float4 a = *(const float4*)p;
    float4 b = *(const float4*)(p + 4);
    union { short8 v; u16 u[8]; } r;
    r.u[0] = f2bf(a.x); r.u[1] = f2bf(a.y); r.u[2] = f2bf(a.z); r.u[3] = f2bf(a.w);
    r.u[4] = f2bf(b.x); r.u[5] = f2bf(b.y); r.u[6] = f2bf(b.z); r.u[7] = f2bf(b.w);
    return r.v;
}
__device__ __forceinline__ short8 load_afrag(const u16* p) {
    return *(const short8*)p;
}

template <int PHASES, typename XT>
__global__ __launch_bounds__(256) void gemm_mfma_kernel(
    const XT* __restrict__ X0, const XT* __restrict__ X1,
    const u16* __restrict__ Wpack,       // PHASES contiguous packed panels
    const float* __restrict__ a_s, const float* __restrict__ a_d,
    u16* __restrict__ H, float* __restrict__ Ss, float* __restrict__ Sd, int N) {

    __shared__ u16 Wlds[PHASES * 4 * 8 * 64 * 8];   // 32 KiB per phase
    const int tid  = threadIdx.x;
    const int lane = tid & 63;
    const int wv   = tid >> 6;

    {
        const uint4* s = (const uint4*)Wpack;
        uint4* d = (uint4*)Wlds;
        for (int i = tid; i < PHASES * 2048; i += 256) d[i] = s[i];
    }
    __syncthreads();

    const int rb = blockIdx.x * 64 + wv * 16;
    int lrow = rb + (lane & 15); if (lrow >= N) lrow = N - 1;   // clamped load row
    const int koff = (lane >> 4) * 8;

    f32x4 acc[8];
#pragma unroll
    for (int c = 0; c < 8; ++c) acc[c] = (f32x4){0.f, 0.f, 0.f, 0.f};

#pragma unroll
    for (int p = 0; p < PHASES; ++p) {
        const XT* xrow = ((p == 0) ? X0 : X1) + (size_t)lrow * DD;
#pragma unroll
        for (int t = 0; t < 4; ++t) {
            short8 af = load_afrag(xrow + t * 32 + koff);
            const u16* wb = &Wlds[(((p * 4 + t) * 8) * 64 + lane) * 8];
#pragma unroll
            for (int c = 0; c < 8; ++c) {
                short8 bf = *(const short8*)(wb + c * 512);
                acc[c] = __builtin_amdgcn_mfma_f32_16x16x32_bf16(af, bf, acc[c], 0, 0, 0);
            }
        }
    }

    // epilogue: C/D layout col = lane&15, row = rb + (lane>>4)*4 + r
    const int colb = lane & 15;
    const int r0 = rb + (lane >> 4) * 4;
    float ps[4] = {0.f, 0.f, 0.f, 0.f};
    float pd[4] = {0.f, 0.f, 0.f, 0.f};
#pragma unroll
    for (int c = 0; c < 8; ++c) {
        float as_c = a_s[c * 16 + colb];
        float ad_c = a_d[c * 16 + colb];
#pragma unroll
        for (int r = 0; r < 4; ++r) {
            float v = acc[c][r];
            ps[r] += v * as_c;
            pd[r] += v * ad_c;
            int row = r0 + r;
            if (row < N) H[(size_t)row * DD + c * 16 + colb] = f2bf(v);
        }
    }
#pragma unroll
    for (int r = 0; r < 4; ++r) {
        float s1 = ps[r], s2 = pd[r];
#pragma unroll
        for (int m = 1; m < 16; m <<= 1) {
            s1 += __shfl_xor(s1, m, 64);
            s2 += __shfl_xor(s2, m, 64);
        }
        int row = r0 + r;
        if (colb == 0 && row < N) { Ss[row] = s1; Sd[row] = s2; }
    }
}

// ---------------------------------------------------------------------------
// Fused GAT edge stage: one wave per dst node, single pass, bf16 H gathers
// (4 B/lane), f32 softmax. OT = u16 (bf16 out) or float (final layer).
// ---------------------------------------------------------------------------
__device__ __forceinline__ float lrelu(float v) {
    return v >= 0.f ? v : LRELU_SLOPE * v;
}
__device__ __forceinline__ void store_out(u16* OUT, size_t idx, float vx, float vy) {
    u32 pk = (u32)f2bf(vx) | ((u32)f2bf(vy) << 16);
    ((u32*)OUT)[idx] = pk;
}
__device__ __forceinline__ void store_out(float* OUT, size_t idx, float vx, float vy) {
    ((float2*)OUT)[idx] = make_float2(vx, vy);
}

template <typename OT>
__global__ __launch_bounds__(256) void gat_edge_kernel(
    const u16* __restrict__ H, const float* __restrict__ Ss, const float* __restrict__ Sd,
    const int* __restrict__ rowp, const int* __restrict__ esrc,
    const float* __restrict__ bias, OT* __restrict__ OUT, int N) {

    const int lane = threadIdx.x & 63;
    const int node = (blockIdx.x * blockDim.x + threadIdx.x) >> 6;
    if (node >= N) return;

    const int beg = rowp[node];
    const int end = rowp[node + 1];
    const float sd = Sd[node];

    const u32* H1 = (const u32*)H;     // 2 bf16 per u32; lane owns cols 2l, 2l+1
    float d0 = 0.f, d1 = 0.f, d2 = 0.f, d3 = 0.f;
    float2 A0 = {0.f, 0.f}, A1 = {0.f, 0.f}, A2 = {0.f, 0.f}, A3 = {0.f, 0.f};

    int j = beg;
    for (; j + 4 <= end; j += 4) {
        int s0 = esrc[j], s1 = esrc[j + 1], s2 = esrc[j + 2], s3 = esrc[j + 3];
        float p0 = __expf(lrelu(Ss[s0] + sd));
        float p1 = __expf(lrelu(Ss[s1] + sd));
        float p2 = __expf(lrelu(Ss[s2] + sd));
        float p3 = __expf(lrelu(Ss[s3] + sd));
        u32 h0 = H1[(size_t)s0 * 64 + lane];
        u32 h1 = H1[(size_t)s1 * 64 + lane];
        u32 h2 = H1[(size_t)s2 * 64 + lane];
        u32 h3 = H1[(size_t)s3 * 64 + lane];
        d0 += p0; A0.x += p0 * bf2f(h0 & 0xffff); A0.y += p0 * bf2f(h0 >> 16);
        d1 += p1; A1.x += p1 * bf2f(h1 & 0xffff); A1.y += p1 * bf2f(h1 >> 16);
        d2 += p2; A2.x += p2 * bf2f(h2 & 0xffff); A2.y += p2 * bf2f(h2 >> 16);
        d3 += p3; A3.x += p3 * bf2f(h3 & 0xffff); A3.y += p3 * bf2f(h3 >> 16);
    }
    for (; j < end; ++j) {
        int s = esrc[j];
        float p = __expf(lrelu(Ss[s] + sd));
        u32 hv = H1[(size_t)s * 64 + lane];
        d0 += p; A0.x += p * bf2f(hv & 0xffff); A0.y += p * bf2f(hv >> 16);
    }

    float denom = (d0 + d1) + (d2 + d3);
    float ax = (A0.x + A1.x) + (A2.x + A3.x);
    float ay = (A0.y + A1.y) + (A2.y + A3.y);
    float inv = 1.f / denom;
    float b0 = bias[2 * lane], b1 = bias[2 * lane + 1];
    store_out(OUT, (size_t)node * 64 + lane, ax * inv + b0, ay * inv + b1);
}

// ---------------------------------------------------------------------------
extern "C" void kernel_launch(void* const* d_in, const int* in_sizes, int n_in,
                              void* d_out, int out_size, void* d_ws, size_t ws_size,
                              hipStream_t stream) {
    const float* x    = (const float*)d_in[0];
    const void*  ei   = d_in[1];
    const float* We   = (const float*)d_in[2];
    const float* ae_s = (const float*)d_in[3];
    const float* ae_d = (const float*)d_in[4];
    const float* be   = (const float*)d_in[5];
    const float* Wp   = (const float*)d_in[6];
    const float* ap_s = (const float*)d_in[7];
    const float* ap_d = (const float*)d_in[8];
    const float* bp   = (const float*)d_in[9];
    const float* Wd   = (const float*)d_in[10];
    const float* ad_s = (const float*)d_in[11];
    const float* ad_d = (const float*)d_in[12];
    const float* bd   = (const float*)d_in[13];

    const int N = in_sizes[0] / DD;
    const int E = in_sizes[1] / 2;
    const int ETOT = E + N;
    const int NB = (N + SE - 1) / SE;          // scan blocks (<=256 for N<=262144)
    const int bdiv = (N + NBK - 1) / NBK;      // dst range per bucket

    // ---- workspace carve ----
    char* w = (char*)d_ws;
    u16*  Wpack = (u16*)w;   w += (size_t)4 * 16384 * 2;        // 128 KiB packed weights
    u16*  Hb    = (u16*)w;   w += (size_t)N * DD * 2;           // bf16 H
    u16*  f_enc = (u16*)w;   w += (size_t)N * DD * 2;           // bf16 encoded
    u16*  f_x   = (u16*)w;   w += (size_t)N * DD * 2;           // bf16 hidden
    float* Ss   = (float*)w; w += (size_t)N * 4;
    float* Sd   = (float*)w; w += (size_t)N * 4;
    int*  rowp  = (int*)w;   w += (size_t)(N + 1) * 4;
    int*  esrc  = (int*)w;   w += (size_t)ETOT * 4;
    int*  flag  = (int*)w;   w += 256;
    int*  bsum  = (int*)w;   w += 256 * 4;
    int*  boff  = (int*)w;   w += 256 * 4;
    int*  bcnt  = (int*)w;   w += NBK * 4;
    int2* pairs = (int2*)w;  w += (size_t)NBK * BCAP * 8;       // 16.8 MiB
    if ((size_t)(w - (char*)d_ws) > ws_size) return;            // graceful failure

    // build-phase aliases (dead before first GEMM reads them)
    int* deg    = (int*)Ss;
    int* cursor = (int*)Sd;

    float* out = (float*)d_out;

    // ---- CSR over dst (shared by all 4 layers), locality-bucketed ----
    {
        detect_i64_kernel<<<1, 256, 0, stream>>>((const int*)ei, flag, E);
        zero2_kernel<<<(N + 255) / 256, 256, 0, stream>>>(deg, N, bcnt, NBK);
        bucket_hist_kernel<<<(ETOT + 255) / 256, 256, 0, stream>>>(ei, flag, deg, bcnt,
                                                                   pairs, E, N, bdiv);
        block_sum_kernel<<<NB, 256, 0, stream>>>(deg, bsum, N);
        scan_bsum_kernel<<<1, 256, 0, stream>>>(bsum, boff, NB);
        scan_write_kernel<<<NB, 256, 0, stream>>>(deg, boff, rowp, cursor, N);
        bucket_scatter_kernel<<<NBK, 256, 0, stream>>>(pairs, bcnt, cursor, esrc);
    }

    // ---- pack weights to bf16 MFMA fragment layout ----
    pack_w_kernel<<<128, 64, 0, stream>>>(We, Wp, Wd, Wpack);

    const int gG = (N + 63) / 64;
    const int gE = (N + 3) / 4;

    // ---- layer 1: encode (x f32 -> f_enc bf16) ----
    gemm_mfma_kernel<1, float><<<gG, 256, 0, stream>>>(x, x, Wpack + 0 * 16384,
                                                       ae_s, ae_d, Hb, Ss, Sd, N);
    gat_edge_kernel<u16><<<gE, 256, 0, stream>>>(Hb, Ss, Sd, rowp, esrc, be, f_enc, N);

    // ---- layer 2: processor 1 (concat[f_enc, f_enc] -> f_x) ----
    gemm_mfma_kernel<2, u16><<<gG, 256, 0, stream>>>(f_enc, f_enc, Wpack + 1 * 16384,
                                                     ap_s, ap_d, Hb, Ss, Sd, N);
    gat_edge_kernel<u16><<<gE, 256, 0, stream>>>(Hb, Ss, Sd, rowp, esrc, bp, f_x, N);

    // ---- layer 3: processor 2 (concat[f_x, f_enc] -> f_x) ----
    gemm_mfma_kernel<2, u16><<<gG, 256, 0, stream>>>(f_x, f_enc, Wpack + 1 * 16384,
                                                     ap_s, ap_d, Hb, Ss, Sd, N);
    gat_edge_kernel<u16><<<gE, 256, 0, stream>>>(Hb, Ss, Sd, rowp, esrc, bp, f_x, N);

    // ---- layer 4: decode (f_x -> out f32) ----
    gemm_mfma_kernel<1, u16><<<gG, 256, 0, stream>>>(f_x, f_x, Wpack + 3 * 16384,
                                                     ad_s, ad_d, Hb, Ss, Sd, N);
    gat_edge_kernel<float><<<gE, 256, 0, stream>>>(Hb, Ss, Sd, rowp, esrc, bd, out, N);
}

// Round 7
// 331.099 us; speedup vs baseline: 2.2356x; 2.2356x over previous
//
#include <hip/hip_runtime.h>

#define DD 128            // feature dim
#define LRELU_SLOPE 0.2f
#define SE 1024           // degrees per scan block
#define NPART 8           // XCD partitions for CSR build passes

typedef unsigned short u16;
typedef unsigned int   u32;
typedef __attribute__((ext_vector_type(8))) short short8;   // 8 bf16 (4 VGPRs)
typedef __attribute__((ext_vector_type(4))) float f32x4;    // MFMA C/D

__device__ __forceinline__ u16 f2bf(float f) {              // RNE f32->bf16
    union { float f; u32 u; } v; v.f = f;
    u32 r = (v.u + 0x7fffu + ((v.u >> 16) & 1u)) >> 16;
    return (u16)r;
}
__device__ __forceinline__ float bf2f(u32 hi16) {           // bf16 bits -> f32
    union { u32 u; float f; } v; v.u = hi16 << 16;
    return v.f;
}

// ---------------------------------------------------------------------------
// Edge-index dtype detection (int64 vs int32) — high words all zero => int64.
// ---------------------------------------------------------------------------
__global__ void detect_i64_kernel(const int* __restrict__ ei32, int* __restrict__ flag, int E) {
    __shared__ int any_nz;
    if (threadIdx.x == 0) any_nz = 0;
    __syncthreads();
    int nz = 0;
    int kmax = (E < 4096) ? E : 4096;
    for (int k = threadIdx.x; k < kmax; k += blockDim.x)
        if (ei32[2 * k + 1] != 0) nz = 1;
    if (nz) atomicOr(&any_nz, 1);
    __syncthreads();
    if (threadIdx.x == 0) *flag = any_nz ? 0 : 1;
}

__device__ __forceinline__ int load_dst(const void* ei, int is64, int E, int i) {
    return is64 ? (int)((const long long*)ei)[E + i] : ((const int*)ei)[E + i];
}
__device__ __forceinline__ int load_src(const void* ei, int is64, int E, int i) {
    return is64 ? (int)((const long long*)ei)[i] : ((const int*)ei)[i];
}

__global__ void zero_int_kernel(int* __restrict__ p, int n) {
    int i = blockIdx.x * blockDim.x + threadIdx.x;
    if (i < n) p[i] = 0;
}

// ---------------------------------------------------------------------------
// CSR build, XCD-partitioned passes: block b handles only edges with
// dst/pdiv == (b & 7). With round-robin blockIdx->XCD mapping, each XCD's
// deg/cursor atomics and esrc writes stay in its own L2 slice (no cross-XCD
// line bouncing). Edge-list re-reads are L3-resident (measured r5: 3.4MB
// FETCH for a 13.6MB list). Correct regardless of the actual mapping.
// ---------------------------------------------------------------------------
__global__ void hist_part_kernel(const void* __restrict__ ei, const int* __restrict__ flag,
                                 int* __restrict__ deg, int E, int N, int pdiv) {
    int part = blockIdx.x & (NPART - 1);
    int i = (blockIdx.x >> 3) * blockDim.x + threadIdx.x;
    int tot = E + N;
    if (i >= tot) return;
    int f = *flag;
    int d = (i < E) ? load_dst(ei, f, E, i) : (i - E);
    if ((unsigned)d >= (unsigned)N) return;
    if (d / pdiv != part) return;
    atomicAdd(&deg[d], 1);
}

__global__ void scatter_part_kernel(const void* __restrict__ ei, const int* __restrict__ flag,
                                    int* __restrict__ cursor, int* __restrict__ esrc,
                                    int E, int N, int pdiv) {
    int part = blockIdx.x & (NPART - 1);
    int i = (blockIdx.x >> 3) * blockDim.x + threadIdx.x;
    int tot = E + N;
    if (i >= tot) return;
    int f = *flag;
    int s, d;
    if (i < E) {
        d = load_dst(ei, f, E, i);
        if ((unsigned)d >= (unsigned)N || d / pdiv != part) return;
        s = load_src(ei, f, E, i);
        if ((unsigned)s >= (unsigned)N) return;
    } else {
        s = d = i - E;
        if (d / pdiv != part) return;
    }
    int pos = atomicAdd(&cursor[d], 1);
    esrc[pos] = s;
}

// stage 1: per-block sums of 1024 degrees (coalesced)
__global__ __launch_bounds__(256) void block_sum_kernel(const int* __restrict__ deg,
                                                        int* __restrict__ bsum, int N) {
    int t = threadIdx.x;
    int base = blockIdx.x * SE;
    int s = 0;
#pragma unroll
    for (int i = 0; i < 4; ++i) {
        int idx = base + i * 256 + t;
        if (idx < N) s += deg[idx];
    }
#pragma unroll
    for (int m = 1; m < 64; m <<= 1) s += __shfl_xor(s, m, 64);
    __shared__ int ws[4];
    if ((t & 63) == 0) ws[t >> 6] = s;
    __syncthreads();
    if (t == 0) bsum[blockIdx.x] = ws[0] + ws[1] + ws[2] + ws[3];
}

// stage 2: single small block — exclusive scan of nb (<=256) block sums
__global__ __launch_bounds__(256) void scan_bsum_kernel(const int* __restrict__ bsum,
                                                        int* __restrict__ boff, int nb) {
    int t = threadIdx.x;
    int lane = t & 63;
    int v = (t < nb) ? bsum[t] : 0;
    int incl = v;
#pragma unroll
    for (int m = 1; m < 64; m <<= 1) {
        int u = __shfl_up(incl, m, 64);
        if (lane >= m) incl += u;
    }
    __shared__ int wtot[4];
    if (lane == 63) wtot[t >> 6] = incl;
    __syncthreads();
    int woff = 0;
    for (int w = 0; w < (t >> 6); ++w) woff += wtot[w];
    if (t < nb) boff[t] = incl - v + woff;
}

// stage 3: intra-block exclusive scan (4 elems/thread via int4) + block offset
__global__ __launch_bounds__(256) void scan_write_kernel(const int* __restrict__ deg,
                                                         const int* __restrict__ boff,
                                                         int* __restrict__ rowp,
                                                         int* __restrict__ cursor, int N) {
    int t = threadIdx.x;
    int base = blockIdx.x * SE + t * 4;
    int v0 = 0, v1 = 0, v2 = 0, v3 = 0;
    if (base + 3 < N) {
        int4 q = *(const int4*)(deg + base);
        v0 = q.x; v1 = q.y; v2 = q.z; v3 = q.w;
    } else {
        if (base + 0 < N) v0 = deg[base + 0];
        if (base + 1 < N) v1 = deg[base + 1];
        if (base + 2 < N) v2 = deg[base + 2];
    }
    int tsum = v0 + v1 + v2 + v3;
    int lane = t & 63;
    int incl = tsum;
#pragma unroll
    for (int m = 1; m < 64; m <<= 1) {
        int u = __shfl_up(incl, m, 64);
        if (lane >= m) incl += u;
    }
    __shared__ int wtot[4];
    if (lane == 63) wtot[t >> 6] = incl;
    __syncthreads();
    int woff = 0;
    for (int w = 0; w < (t >> 6); ++w) woff += wtot[w];
    int run = boff[blockIdx.x] + woff + incl - tsum;
    int vs[4] = {v0, v1, v2, v3};
    int idx = base;
#pragma unroll
    for (int i = 0; i < 4; ++i, ++idx) {
        if (idx < N) {
            rowp[idx] = run; cursor[idx] = run; run += vs[i];
            if (idx == N - 1) rowp[N] = run;
        }
    }
}

// ---------------------------------------------------------------------------
// Weight pre-pack: W panels (f32 row-major [K][128]) -> bf16 MFMA B-fragment
// order. Fragment (panel, t, c): lane l, elem j holds
//   W[t*32 + (l>>4)*8 + j][c*16 + (l&15)]
// flat: Wpack[(((panel*4 + t)*8 + c)*64 + l)*8 + j]
// panels: 0=We, 1=Wp[0:128], 2=Wp[128:256], 3=Wd. 128 blocks x 64 threads.
// ---------------------------------------------------------------------------
__global__ void pack_w_kernel(const float* __restrict__ We, const float* __restrict__ Wp,
                              const float* __restrict__ Wd, u16* __restrict__ Wpack) {
    int blk = blockIdx.x;
    int l = threadIdx.x;
    int panel = blk >> 5, t = (blk >> 3) & 3, c = blk & 7;
    const float* src = (panel == 0) ? We : (panel == 3) ? Wd : Wp + (size_t)(panel - 1) * 128 * DD;
    u16* dst = Wpack + ((((size_t)panel * 4 + t) * 8 + c) * 64 + l) * 8;
    int krow = t * 32 + (l >> 4) * 8;
    int col = c * 16 + (l & 15);
#pragma unroll
    for (int j = 0; j < 8; ++j)
        dst[j] = f2bf(src[(size_t)(krow + j) * DD + col]);
}

// ---------------------------------------------------------------------------
// MFMA GEMM + attention scores.
// H[row] = Xcat[row] @ W  (bf16 MFMA, f32 acc); Ss/Sd = H . a_s / a_d (f32).
// Block = 256 thr = 4 waves; each wave one 16-row x 128-col tile.
// ---------------------------------------------------------------------------
__device__ __forceinline__ short8 load_afrag(const float* p) {
    float4 a = *(const float4*)p;
    float4 b = *(const float4*)(p + 4);
    union { short8 v; u16 u[8]; } r;
    r.u[0] = f2bf(a.x); r.u[1] = f2bf(a.y); r.u[2] = f2bf(a.z); r.u[3] = f2bf(a.w);
    r.u[4] = f2bf(b.x); r.u[5] = f2bf(b.y); r.u[6] = f2bf(b.z); r.u[7] = f2bf(b.w);
    return r.v;
}
__device__ __forceinline__ short8 load_afrag(const u16* p) {
    return *(const short8*)p;
}

template <int PHASES, typename XT>
__global__ __launch_bounds__(256) void gemm_mfma_kernel(
    const XT* __restrict__ X0, const XT* __restrict__ X1,
    const u16* __restrict__ Wpack,       // PHASES contiguous packed panels
    const float* __restrict__ a_s, const float* __restrict__ a_d,
    u16* __restrict__ H, float* __restrict__ Ss, float* __restrict__ Sd, int N) {

    __shared__ u16 Wlds[PHASES * 4 * 8 * 64 * 8];   // 32 KiB per phase
    const int tid  = threadIdx.x;
    const int lane = tid & 63;
    const int wv   = tid >> 6;

    {
        const uint4* s = (const uint4*)Wpack;
        uint4* d = (uint4*)Wlds;
        for (int i = tid; i < PHASES * 2048; i += 256) d[i] = s[i];
    }
    __syncthreads();

    const int rb = blockIdx.x * 64 + wv * 16;
    int lrow = rb + (lane & 15); if (lrow >= N) lrow = N - 1;   // clamped load row
    const int koff = (lane >> 4) * 8;

    f32x4 acc[8];
#pragma unroll
    for (int c = 0; c < 8; ++c) acc[c] = (f32x4){0.f, 0.f, 0.f, 0.f};

#pragma unroll
    for (int p = 0; p < PHASES; ++p) {
        const XT* xrow = ((p == 0) ? X0 : X1) + (size_t)lrow * DD;
#pragma unroll
        for (int t = 0; t < 4; ++t) {
            short8 af = load_afrag(xrow + t * 32 + koff);
            const u16* wb = &Wlds[(((p * 4 + t) * 8) * 64 + lane) * 8];
#pragma unroll
            for (int c = 0; c < 8; ++c) {
                short8 bf = *(const short8*)(wb + c * 512);
                acc[c] = __builtin_amdgcn_mfma_f32_16x16x32_bf16(af, bf, acc[c], 0, 0, 0);
            }
        }
    }

    // epilogue: C/D layout col = lane&15, row = rb + (lane>>4)*4 + r
    const int colb = lane & 15;
    const int r0 = rb + (lane >> 4) * 4;
    float ps[4] = {0.f, 0.f, 0.f, 0.f};
    float pd[4] = {0.f, 0.f, 0.f, 0.f};
#pragma unroll
    for (int c = 0; c < 8; ++c) {
        float as_c = a_s[c * 16 + colb];
        float ad_c = a_d[c * 16 + colb];
#pragma unroll
        for (int r = 0; r < 4; ++r) {
            float v = acc[c][r];
            ps[r] += v * as_c;
            pd[r] += v * ad_c;
            int row = r0 + r;
            if (row < N) H[(size_t)row * DD + c * 16 + colb] = f2bf(v);
        }
    }
#pragma unroll
    for (int r = 0; r < 4; ++r) {
        float s1 = ps[r], s2 = pd[r];
#pragma unroll
        for (int m = 1; m < 16; m <<= 1) {
            s1 += __shfl_xor(s1, m, 64);
            s2 += __shfl_xor(s2, m, 64);
        }
        int row = r0 + r;
        if (colb == 0 && row < N) { Ss[row] = s1; Sd[row] = s2; }
    }
}

// ---------------------------------------------------------------------------
// Fused GAT edge stage: one wave per dst node, single pass, bf16 H gathers
// (4 B/lane), f32 softmax. OT = u16 (bf16 out) or float (final layer).
// ---------------------------------------------------------------------------
__device__ __forceinline__ float lrelu(float v) {
    return v >= 0.f ? v : LRELU_SLOPE * v;
}
__device__ __forceinline__ void store_out(u16* OUT, size_t idx, float vx, float vy) {
    u32 pk = (u32)f2bf(vx) | ((u32)f2bf(vy) << 16);
    ((u32*)OUT)[idx] = pk;
}
__device__ __forceinline__ void store_out(float* OUT, size_t idx, float vx, float vy) {
    ((float2*)OUT)[idx] = make_float2(vx, vy);
}

template <typename OT>
__global__ __launch_bounds__(256) void gat_edge_kernel(
    const u16* __restrict__ H, const float* __restrict__ Ss, const float* __restrict__ Sd,
    const int* __restrict__ rowp, const int* __restrict__ esrc,
    const float* __restrict__ bias, OT* __restrict__ OUT, int N) {

    const int lane = threadIdx.x & 63;
    const int node = (blockIdx.x * blockDim.x + threadIdx.x) >> 6;
    if (node >= N) return;

    const int beg = rowp[node];
    const int end = rowp[node + 1];
    const float sd = Sd[node];

    const u32* H1 = (const u32*)H;     // 2 bf16 per u32; lane owns cols 2l, 2l+1
    float d0 = 0.f, d1 = 0.f, d2 = 0.f, d3 = 0.f;
    float2 A0 = {0.f, 0.f}, A1 = {0.f, 0.f}, A2 = {0.f, 0.f}, A3 = {0.f, 0.f};

    int j = beg;
    for (; j + 4 <= end; j += 4) {
        int s0 = esrc[j], s1 = esrc[j + 1], s2 = esrc[j + 2], s3 = esrc[j + 3];
        float p0 = __expf(lrelu(Ss[s0] + sd));
        float p1 = __expf(lrelu(Ss[s1] + sd));
        float p2 = __expf(lrelu(Ss[s2] + sd));
        float p3 = __expf(lrelu(Ss[s3] + sd));
        u32 h0 = H1[(size_t)s0 * 64 + lane];
        u32 h1 = H1[(size_t)s1 * 64 + lane];
        u32 h2 = H1[(size_t)s2 * 64 + lane];
        u32 h3 = H1[(size_t)s3 * 64 + lane];
        d0 += p0; A0.x += p0 * bf2f(h0 & 0xffff); A0.y += p0 * bf2f(h0 >> 16);
        d1 += p1; A1.x += p1 * bf2f(h1 & 0xffff); A1.y += p1 * bf2f(h1 >> 16);
        d2 += p2; A2.x += p2 * bf2f(h2 & 0xffff); A2.y += p2 * bf2f(h2 >> 16);
        d3 += p3; A3.x += p3 * bf2f(h3 & 0xffff); A3.y += p3 * bf2f(h3 >> 16);
    }
    for (; j < end; ++j) {
        int s = esrc[j];
        float p = __expf(lrelu(Ss[s] + sd));
        u32 hv = H1[(size_t)s * 64 + lane];
        d0 += p; A0.x += p * bf2f(hv & 0xffff); A0.y += p * bf2f(hv >> 16);
    }

    float denom = (d0 + d1) + (d2 + d3);
    float ax = (A0.x + A1.x) + (A2.x + A3.x);
    float ay = (A0.y + A1.y) + (A2.y + A3.y);
    float inv = 1.f / denom;
    float b0 = bias[2 * lane], b1 = bias[2 * lane + 1];
    store_out(OUT, (size_t)node * 64 + lane, ax * inv + b0, ay * inv + b1);
}

// ---------------------------------------------------------------------------
extern "C" void kernel_launch(void* const* d_in, const int* in_sizes, int n_in,
                              void* d_out, int out_size, void* d_ws, size_t ws_size,
                              hipStream_t stream) {
    const float* x    = (const float*)d_in[0];
    const void*  ei   = d_in[1];
    const float* We   = (const float*)d_in[2];
    const float* ae_s = (const float*)d_in[3];
    const float* ae_d = (const float*)d_in[4];
    const float* be   = (const float*)d_in[5];
    const float* Wp   = (const float*)d_in[6];
    const float* ap_s = (const float*)d_in[7];
    const float* ap_d = (const float*)d_in[8];
    const float* bp   = (const float*)d_in[9];
    const float* Wd   = (const float*)d_in[10];
    const float* ad_s = (const float*)d_in[11];
    const float* ad_d = (const float*)d_in[12];
    const float* bd   = (const float*)d_in[13];

    const int N = in_sizes[0] / DD;
    const int E = in_sizes[1] / 2;
    const int ETOT = E + N;
    const int NB = (N + SE - 1) / SE;          // scan blocks (<=256 for N<=262144)
    const int pdiv = (N + NPART - 1) / NPART;  // dst range per XCD partition

    // ---- workspace carve ----
    char* w = (char*)d_ws;
    u16*  Wpack = (u16*)w;   w += (size_t)4 * 16384 * 2;        // 128 KiB packed weights
    u16*  Hb    = (u16*)w;   w += (size_t)N * DD * 2;           // bf16 H
    u16*  f_enc = (u16*)w;   w += (size_t)N * DD * 2;           // bf16 encoded
    u16*  f_x   = (u16*)w;   w += (size_t)N * DD * 2;           // bf16 hidden
    float* Ss   = (float*)w; w += (size_t)N * 4;
    float* Sd   = (float*)w; w += (size_t)N * 4;
    int*  rowp  = (int*)w;   w += (size_t)(N + 1) * 4;
    int*  esrc  = (int*)w;   w += (size_t)ETOT * 4;
    int*  flag  = (int*)w;   w += 256;
    int*  bsum  = (int*)w;   w += 256 * 4;
    int*  boff  = (int*)w;   w += 256 * 4;
    if ((size_t)(w - (char*)d_ws) > ws_size) return;            // graceful failure

    // build-phase aliases (dead before first GEMM reads them)
    int* deg    = (int*)Ss;
    int* cursor = (int*)Sd;

    float* out = (float*)d_out;

    // ---- CSR over dst (shared by all 4 layers), XCD-partitioned ----
    {
        int gPart = ((ETOT + 255) / 256) * NPART;
        detect_i64_kernel<<<1, 256, 0, stream>>>((const int*)ei, flag, E);
        zero_int_kernel<<<(N + 255) / 256, 256, 0, stream>>>(deg, N);
        hist_part_kernel<<<gPart, 256, 0, stream>>>(ei, flag, deg, E, N, pdiv);
        block_sum_kernel<<<NB, 256, 0, stream>>>(deg, bsum, N);
        scan_bsum_kernel<<<1, 256, 0, stream>>>(bsum, boff, NB);
        scan_write_kernel<<<NB, 256, 0, stream>>>(deg, boff, rowp, cursor, N);
        scatter_part_kernel<<<gPart, 256, 0, stream>>>(ei, flag, cursor, esrc, E, N, pdiv);
    }

    // ---- pack weights to bf16 MFMA fragment layout ----
    pack_w_kernel<<<128, 64, 0, stream>>>(We, Wp, Wd, Wpack);

    const int gG = (N + 63) / 64;
    const int gE = (N + 3) / 4;

    // ---- layer 1: encode (x f32 -> f_enc bf16) ----
    gemm_mfma_kernel<1, float><<<gG, 256, 0, stream>>>(x, x, Wpack + 0 * 16384,
                                                       ae_s, ae_d, Hb, Ss, Sd, N);
    gat_edge_kernel<u16><<<gE, 256, 0, stream>>>(Hb, Ss, Sd, rowp, esrc, be, f_enc, N);

    // ---- layer 2: processor 1 (concat[f_enc, f_enc] -> f_x) ----
    gemm_mfma_kernel<2, u16><<<gG, 256, 0, stream>>>(f_enc, f_enc, Wpack + 1 * 16384,
                                                     ap_s, ap_d, Hb, Ss, Sd, N);
    gat_edge_kernel<u16><<<gE, 256, 0, stream>>>(Hb, Ss, Sd, rowp, esrc, bp, f_x, N);

    // ---- layer 3: processor 2 (concat[f_x, f_enc] -> f_x) ----
    gemm_mfma_kernel<2, u16><<<gG, 256, 0, stream>>>(f_x, f_enc, Wpack + 1 * 16384,
                                                     ap_s, ap_d, Hb, Ss, Sd, N);
    gat_edge_kernel<u16><<<gE, 256, 0, stream>>>(Hb, Ss, Sd, rowp, esrc, bp, f_x, N);

    // ---- layer 4: decode (f_x -> out f32) ----
    gemm_mfma_kernel<1, u16><<<gG, 256, 0, stream>>>(f_x, f_x, Wpack + 3 * 16384,
                                                     ad_s, ad_d, Hb, Ss, Sd, N);
    gat_edge_kernel<float><<<gE, 256, 0, stream>>>(Hb, Ss, Sd, rowp, esrc, bd, out, N);
}